// Round 9
// baseline (836.780 us; speedup 1.0000x reference)
//
#include <hip/hip_runtime.h>

// GNNCASimple — fused per-node pipeline (bf16 MFMA, fp32 accum), fp32 I/O.
// r20: FUSED agg+transform for steps 1-3. Budget after r19: xform 4x63=252us,
// agg 4x~60=240us, both ~90% stalled on DIFFERENT resources (xform: MFMA dep
// chains @0.65TB/s; agg: L3 gather @~3.4TB/s), serialized. Fusion: each
// transform block gathers its own 64 nodes' h = segsum(q_prev[src])+pw2+b_post
// into an LDS H tile as phase 0 (q_prev globally complete at kernel boundary),
// then runs the r12 3-stage transform from H. Gather of one block overlaps
// MFMA of 2 co-resident blocks (3 blocks/CU) -> gather hides in the stall.
// Kills 3 agg launches + 3 h round-trips (77MB). q double-buffered (qA/qB);
// pw2 single (blocks touch only own rows). H = u32[64][36] (stride 36 -> 2-way
// banks, free; 16B-aligned bfrag reads), aliased as stA after last H read.
// LDS 52224 -> 3 blocks/CU. Summation order == agg_k bitwise.
// Step 0: r19 128-tile xform (hbf input, 63us). Final: standalone agg (fp32 out).
// Falsifier: fxform >= ~130us => overlap theory dead.

#define NN 100000
#define NPAD 100096               // 782 * 128
#define FS 64
#define HH 256
#define NE 1600000
#define NSTEPS 4
#define GA 128                    // fillA blocks
#define EPB (NE / GA)             // 12500 edges per fillA block
#define BK2SH 9                   // log2(nodes per coarse bucket)
#define BS2 (1 << BK2SH)          // 512
#define NBK2 ((NN + BS2 - 1) / BS2)   // 196 buckets

typedef unsigned short u16;
typedef unsigned int u32;
typedef __attribute__((ext_vector_type(8))) short bfrag;   // 8 bf16 = 4 VGPRs (MFMA A/B)
typedef __attribute__((ext_vector_type(4))) float ffrag;   // 4 fp32 (MFMA C/D)

static __device__ __forceinline__ u16 f2bf(float f) {  // RNE
    union { float f; u32 u; } v; v.f = f;
    return (u16)((v.u + 0x7fffu + ((v.u >> 16) & 1u)) >> 16);
}
static __device__ __forceinline__ float bf2f(u16 h) {
    union { u32 u; float f; } v; v.u = (u32)h << 16; return v.f;
}
static __device__ __forceinline__ u32 pack2bf(float a, float b) {
    return (u32)f2bf(a) | ((u32)f2bf(b) << 16);
}

// ---------------- x (fp32) -> hbf (bf16) ----------------
__global__ void cvt_x_k(const float4* __restrict__ x, uint2* __restrict__ hbf, int n4) {
    int i = blockIdx.x * 256 + threadIdx.x;
    if (i < n4) {
        float4 v = x[i];
        hbf[i] = make_uint2(pack2bf(v.x, v.y), pack2bf(v.z, v.w));
    }
}

// ---------------- all weight transposes (fp32 [K][C] -> bf16 [C][K]) ----------------
__global__ void prep_w_k(const float* __restrict__ W_pre, const float* __restrict__ W_conv,
                         const float* __restrict__ W_post,
                         u16* __restrict__ Wpt, u16* __restrict__ Wct,
                         u16* __restrict__ Wzt, u16* __restrict__ Wp2t) {
    int i = blockIdx.x * 256 + threadIdx.x;
    if (i < 65536) {                       // Wct [256][256]
        int c = i >> 8, k = i & 255;
        Wct[i] = f2bf(W_conv[k * HH + c]);
    } else if (i < 81920) {                // Wpt [256][64]
        int j = i - 65536;
        int c = j >> 6, k = j & 63;
        Wpt[j] = f2bf(W_pre[k * HH + c]);
    } else if (i < 98304) {                // Wzt [64][256]
        int j = i - 81920;
        int c = j >> 8, k = j & 255;
        Wzt[j] = f2bf(W_post[k * FS + c]);
    } else if (i < 114688) {               // Wp2t [64][256]
        int j = i - 98304;
        int c = j >> 8, k = j & 255;
        Wp2t[j] = f2bf(W_post[(HH + k) * FS + c]);
    }
}

// ---------------- fillA ----------------
__global__ __launch_bounds__(256) void fillA_k(const int* __restrict__ dst, const int* __restrict__ src,
                                               int* __restrict__ cntM, int* __restrict__ offM,
                                               u32* __restrict__ tmp) {
    __shared__ int cnt[256];
    __shared__ int sc[256];
    __shared__ int cur[256];
    const int t = threadIdx.x, b = blockIdx.x;
    const int e0 = b * EPB;
    cnt[t] = 0;
    __syncthreads();
    for (int i = t; i < EPB; i += 256) atomicAdd(&cnt[dst[e0 + i] >> BK2SH], 1);
    __syncthreads();
    int v = cnt[t];
    sc[t] = v;
    __syncthreads();
    for (int o = 1; o < 256; o <<= 1) {
        int y = (t >= o) ? sc[t - o] : 0;
        __syncthreads();
        sc[t] += y;
        __syncthreads();
    }
    int excl = sc[t] - v;
    cur[t] = excl;
    if (t < NBK2) {
        cntM[t * GA + b] = v;
        offM[t * GA + b] = excl;
    }
    __syncthreads();
    u32* seg = tmp + (size_t)b * EPB;
    for (int i = t; i < EPB; i += 256) {
        int d = dst[e0 + i], s = src[e0 + i];
        int pos = atomicAdd(&cur[d >> BK2SH], 1);
        seg[pos] = ((u32)(d & (BS2 - 1)) << 23) | (u32)s;
    }
}

// ---------------- bscan ----------------
__global__ void bscan_k(const int* __restrict__ cntM, int* __restrict__ bstart) {
    __shared__ int sh[256];
    const int t = threadIdx.x;
    int tot = 0;
    if (t < NBK2)
        for (int b = 0; b < GA; b++) tot += cntM[t * GA + b];
    sh[t] = tot;
    __syncthreads();
    for (int o = 1; o < 256; o <<= 1) {
        int y = (t >= o) ? sh[t - o] : 0;
        __syncthreads();
        sh[t] += y;
        __syncthreads();
    }
    if (t < NBK2) bstart[t] = sh[t] - tot;
    if (t == 255) bstart[NBK2] = sh[255];
}

// ---------------- fillB ----------------
__global__ __launch_bounds__(256) void fillB_k(const u32* __restrict__ tmp,
                                               const int* __restrict__ cntM, const int* __restrict__ offM,
                                               const int* __restrict__ bstart,
                                               int* __restrict__ offsets, int* __restrict__ srcs) {
    __shared__ int cnt[BS2];
    __shared__ int cur[BS2];
    __shared__ int runlen[GA];
    __shared__ int runoff[GA];
    const int t = threadIdx.x, k = blockIdx.x;
    const int nodeBase = k << BK2SH;
    cnt[t] = 0;
    cnt[t + 256] = 0;
    if (t < GA) {
        runlen[t] = cntM[k * GA + t];
        runoff[t] = offM[k * GA + t];
    }
    __syncthreads();
    const int rsub = t >> 6;
    const int elane = t & 63;
    for (int g = 0; g < GA / 4; g++) {
        int rb = g * 4 + rsub;
        int len = runlen[rb];
        const u32* run = tmp + (size_t)rb * EPB + runoff[rb];
        for (int e = elane; e < len; e += 64) atomicAdd(&cnt[run[e] >> 23], 1);
    }
    __syncthreads();
    int a = cnt[2 * t], b2 = cnt[2 * t + 1];
    int s = a + b2;
    cur[t] = s;
    __syncthreads();
    for (int o = 1; o < 256; o <<= 1) {
        int y = (t >= o) ? cur[t - o] : 0;
        __syncthreads();
        cur[t] += y;
        __syncthreads();
    }
    int exclPair = cur[t] - s;
    __syncthreads();
    const int base = bstart[k];
    int o0 = base + exclPair;
    int o1 = o0 + a;
    int n0 = nodeBase + 2 * t, n1 = n0 + 1;
    if (n0 < NN) offsets[n0] = o0;
    if (n1 < NN) offsets[n1] = o1;
    cur[2 * t] = o0;
    cur[2 * t + 1] = o1;
    __syncthreads();
    for (int g = 0; g < GA / 4; g++) {
        int rb = g * 4 + rsub;
        int len = runlen[rb];
        const u32* run = tmp + (size_t)rb * EPB + runoff[rb];
        for (int e = elane; e < len; e += 64) {
            u32 p = run[e];
            int pos = atomicAdd(&cur[p >> 23], 1);
            srcs[pos] = (int)(p & 0x7FFFFFu);
        }
    }
}

__global__ void final_off_k(int* __restrict__ offsets) {
    if (threadIdx.x == 0) offsets[NN] = NE;
}

// ---------------- step-0 transform (r19 exact: 128-node tile, 8 waves) ----------------
__global__ __launch_bounds__(512, 4) void xform_k(const u16* __restrict__ hbf,     // [NPAD][64]
                                                  const u16* __restrict__ Wpt,
                                                  const float* __restrict__ b_pre,
                                                  const u16* __restrict__ Wct,
                                                  const float* __restrict__ b_conv,
                                                  const u16* __restrict__ Wzt,
                                                  const u16* __restrict__ Wp2t,
                                                  u16* __restrict__ qbf,
                                                  u16* __restrict__ pw2o) {
    __shared__ __align__(16) u16 ts[128 * 264];
    const int t = threadIdx.x;
    const int w = t >> 6, lane = t & 63;
    const int quad = lane >> 4, l16 = lane & 15;
    const int whi = w >> 2;
    const int cw = (w & 3) * 16;
    const int rh = whi * 64;
    const int nodeBase = blockIdx.x * 128;

    {
        ffrag acc[8][2];
#pragma unroll
        for (int mt = 0; mt < 8; mt++) { acc[mt][0] = (ffrag)0.f; acc[mt][1] = (ffrag)0.f; }
#pragma unroll
        for (int ch = 0; ch < 2; ch++) {
            const int kb = ch * 32 + quad * 8;
            bfrag b0 = *(const bfrag*)(Wpt + (size_t)(w * 32 + l16) * FS + kb);
            bfrag b1 = *(const bfrag*)(Wpt + (size_t)(w * 32 + 16 + l16) * FS + kb);
#pragma unroll
            for (int mt = 0; mt < 8; mt++) {
                bfrag a = *(const bfrag*)(hbf + (size_t)(nodeBase + mt * 16 + l16) * FS + kb);
                acc[mt][0] = __builtin_amdgcn_mfma_f32_16x16x32_bf16(a, b0, acc[mt][0], 0, 0, 0);
                acc[mt][1] = __builtin_amdgcn_mfma_f32_16x16x32_bf16(a, b1, acc[mt][1], 0, 0, 0);
            }
        }
#pragma unroll
        for (int nt = 0; nt < 2; nt++) {
            const int col = w * 32 + nt * 16 + l16;
            const float bv = b_pre[col];
#pragma unroll
            for (int mt = 0; mt < 8; mt++)
#pragma unroll
                for (int r = 0; r < 4; r++)
                    ts[(mt * 16 + quad * 4 + r) * 264 + col] = f2bf(fmaxf(acc[mt][nt][r] + bv, 0.f));
        }
    }
    __syncthreads();

    ffrag accm[8][2];
    ffrag accw[4];
    {
#pragma unroll
        for (int mt = 0; mt < 8; mt++) { accm[mt][0] = (ffrag)0.f; accm[mt][1] = (ffrag)0.f; }
#pragma unroll
        for (int mt = 0; mt < 4; mt++) accw[mt] = (ffrag)0.f;
#pragma unroll
        for (int ch = 0; ch < 8; ch++) {
            const int kb = ch * 32 + quad * 8;
            bfrag b0 = *(const bfrag*)(Wct + (size_t)(w * 32 + l16) * HH + kb);
            bfrag b1 = *(const bfrag*)(Wct + (size_t)(w * 32 + 16 + l16) * HH + kb);
            bfrag bw = *(const bfrag*)(Wp2t + (size_t)(cw + l16) * HH + kb);
            {
                bfrag a0 = *(const bfrag*)(ts + (0 * 16 + l16) * 264 + kb);
                bfrag a1 = *(const bfrag*)(ts + (1 * 16 + l16) * 264 + kb);
                bfrag a2 = *(const bfrag*)(ts + (2 * 16 + l16) * 264 + kb);
                bfrag a3 = *(const bfrag*)(ts + (3 * 16 + l16) * 264 + kb);
                if (whi == 0) {
                    accw[0] = __builtin_amdgcn_mfma_f32_16x16x32_bf16(a0, bw, accw[0], 0, 0, 0);
                    accw[1] = __builtin_amdgcn_mfma_f32_16x16x32_bf16(a1, bw, accw[1], 0, 0, 0);
                    accw[2] = __builtin_amdgcn_mfma_f32_16x16x32_bf16(a2, bw, accw[2], 0, 0, 0);
                    accw[3] = __builtin_amdgcn_mfma_f32_16x16x32_bf16(a3, bw, accw[3], 0, 0, 0);
                }
                accm[0][0] = __builtin_amdgcn_mfma_f32_16x16x32_bf16(a0, b0, accm[0][0], 0, 0, 0);
                accm[0][1] = __builtin_amdgcn_mfma_f32_16x16x32_bf16(a0, b1, accm[0][1], 0, 0, 0);
                accm[1][0] = __builtin_amdgcn_mfma_f32_16x16x32_bf16(a1, b0, accm[1][0], 0, 0, 0);
                accm[1][1] = __builtin_amdgcn_mfma_f32_16x16x32_bf16(a1, b1, accm[1][1], 0, 0, 0);
                accm[2][0] = __builtin_amdgcn_mfma_f32_16x16x32_bf16(a2, b0, accm[2][0], 0, 0, 0);
                accm[2][1] = __builtin_amdgcn_mfma_f32_16x16x32_bf16(a2, b1, accm[2][1], 0, 0, 0);
                accm[3][0] = __builtin_amdgcn_mfma_f32_16x16x32_bf16(a3, b0, accm[3][0], 0, 0, 0);
                accm[3][1] = __builtin_amdgcn_mfma_f32_16x16x32_bf16(a3, b1, accm[3][1], 0, 0, 0);
            }
            {
                bfrag a4 = *(const bfrag*)(ts + (4 * 16 + l16) * 264 + kb);
                bfrag a5 = *(const bfrag*)(ts + (5 * 16 + l16) * 264 + kb);
                bfrag a6 = *(const bfrag*)(ts + (6 * 16 + l16) * 264 + kb);
                bfrag a7 = *(const bfrag*)(ts + (7 * 16 + l16) * 264 + kb);
                if (whi == 1) {
                    accw[0] = __builtin_amdgcn_mfma_f32_16x16x32_bf16(a4, bw, accw[0], 0, 0, 0);
                    accw[1] = __builtin_amdgcn_mfma_f32_16x16x32_bf16(a5, bw, accw[1], 0, 0, 0);
                    accw[2] = __builtin_amdgcn_mfma_f32_16x16x32_bf16(a6, bw, accw[2], 0, 0, 0);
                    accw[3] = __builtin_amdgcn_mfma_f32_16x16x32_bf16(a7, bw, accw[3], 0, 0, 0);
                }
                accm[4][0] = __builtin_amdgcn_mfma_f32_16x16x32_bf16(a4, b0, accm[4][0], 0, 0, 0);
                accm[4][1] = __builtin_amdgcn_mfma_f32_16x16x32_bf16(a4, b1, accm[4][1], 0, 0, 0);
                accm[5][0] = __builtin_amdgcn_mfma_f32_16x16x32_bf16(a5, b0, accm[5][0], 0, 0, 0);
                accm[5][1] = __builtin_amdgcn_mfma_f32_16x16x32_bf16(a5, b1, accm[5][1], 0, 0, 0);
                accm[6][0] = __builtin_amdgcn_mfma_f32_16x16x32_bf16(a6, b0, accm[6][0], 0, 0, 0);
                accm[6][1] = __builtin_amdgcn_mfma_f32_16x16x32_bf16(a6, b1, accm[6][1], 0, 0, 0);
                accm[7][0] = __builtin_amdgcn_mfma_f32_16x16x32_bf16(a7, b0, accm[7][0], 0, 0, 0);
                accm[7][1] = __builtin_amdgcn_mfma_f32_16x16x32_bf16(a7, b1, accm[7][1], 0, 0, 0);
            }
        }
    }
    __syncthreads();

    {
#pragma unroll
        for (int nt = 0; nt < 2; nt++) {
            const int col = w * 32 + nt * 16 + l16;
            const float bv = b_conv[col];
#pragma unroll
            for (int mt = 0; mt < 8; mt++)
#pragma unroll
                for (int r = 0; r < 4; r++)
                    ts[(mt * 16 + quad * 4 + r) * 264 + col] = f2bf(fmaxf(accm[mt][nt][r] + bv, 0.f));
        }
    }
    __syncthreads();

    ffrag qa[4];
    {
#pragma unroll
        for (int mt = 0; mt < 4; mt++) qa[mt] = (ffrag)0.f;
#pragma unroll
        for (int ch = 0; ch < 8; ch++) {
            const int kb = ch * 32 + quad * 8;
            bfrag bz = *(const bfrag*)(Wzt + (size_t)(cw + l16) * HH + kb);
#pragma unroll
            for (int mt = 0; mt < 4; mt++) {
                bfrag am = *(const bfrag*)(ts + (rh + mt * 16 + l16) * 264 + kb);
                qa[mt] = __builtin_amdgcn_mfma_f32_16x16x32_bf16(am, bz, qa[mt], 0, 0, 0);
            }
        }
    }
    __syncthreads();

    {
        u16* stgP = ts;
        u16* stgQ = ts + 128 * 72;
#pragma unroll
        for (int mt = 0; mt < 4; mt++)
#pragma unroll
            for (int r = 0; r < 4; r++) {
                const int row = rh + mt * 16 + quad * 4 + r;
                stgP[row * 72 + cw + l16] = f2bf(accw[mt][r]);
                stgQ[row * 72 + cw + l16] = f2bf(qa[mt][r]);
            }
    }
    __syncthreads();

    {
        const u16* stgP = ts;
        const u16* stgQ = ts + 128 * 72;
#pragma unroll
        for (int s = 0; s < 2; s++) {
            const int j = t + s * 512;
            const int row = j >> 3, seg = j & 7;
            if (nodeBase + row < NN) {
                uint4 vp = *(const uint4*)(stgP + row * 72 + seg * 8);
                uint4 vq = *(const uint4*)(stgQ + row * 72 + seg * 8);
                *(uint4*)(pw2o + (size_t)(nodeBase + row) * FS + seg * 8) = vp;
                *(uint4*)(qbf + (size_t)(nodeBase + row) * FS + seg * 8) = vq;
            }
        }
    }
}

// ---------------- FUSED gather + transform (steps 1..3; 64-node tile, 4 waves) ----------------
__global__ __launch_bounds__(256, 3) void fxform_k(const u32* __restrict__ qprev,  // [NPAD][32] u32 pairs
                                                   const int* __restrict__ offsets,
                                                   const int* __restrict__ srcs,
                                                   const u32* __restrict__ pw2p,   // [NPAD][32] u32 pairs (prev)
                                                   const float* __restrict__ b_post,
                                                   const u16* __restrict__ Wpt,
                                                   const float* __restrict__ b_pre,
                                                   const u16* __restrict__ Wct,
                                                   const float* __restrict__ b_conv,
                                                   const u16* __restrict__ Wzt,
                                                   const u16* __restrict__ Wp2t,
                                                   u16* __restrict__ qbf,          // [NPAD][64] (cur)
                                                   u16* __restrict__ pw2o) {       // [NPAD][64] (cur)
    __shared__ __align__(16) char smem[52224];
    u16* ts  = (u16*)smem;                 // [64][264]: p, then m
    u16* Hs  = (u16*)(smem + 33792);       // [64][72]: h bf16 (u32 stride 36); aliased as stA after S1
    u16* stB = (u16*)(smem + 43008);       // [64][72]: q staging
    const int t = threadIdx.x;
    const int wave = t >> 6, lane = t & 63;
    const int quad = lane >> 4, l16 = lane & 15;
    const int half = lane >> 5, c = lane & 31;
    const int nodeBase = blockIdx.x * 64;

    // ---- phase G: h = segsum(qprev[src]) + pw2p + b_post -> Hs (wave handles 16 nodes) ----
    {
        u32* H32 = (u32*)Hs;
        const float2 bp = *(const float2*)&b_post[2 * c];
        for (int i = 0; i < 16; i++) {
            const int node = nodeBase + wave * 16 + i;
            float ax = 0.f, ay = 0.f, bx = 0.f, by = 0.f;
            if (node < NN) {
                const int beg = offsets[node], end = offsets[node + 1];
                int e = beg + half;
                for (; e + 6 < end; e += 8) {
                    int s0 = srcs[e], s1 = srcs[e + 2], s2 = srcs[e + 4], s3 = srcs[e + 6];
                    u32 g0 = qprev[(size_t)s0 * 32 + c];
                    u32 g1 = qprev[(size_t)s1 * 32 + c];
                    u32 g2 = qprev[(size_t)s2 * 32 + c];
                    u32 g3 = qprev[(size_t)s3 * 32 + c];
                    ax += bf2f((u16)g0) + bf2f((u16)g1);
                    ay += bf2f((u16)(g0 >> 16)) + bf2f((u16)(g1 >> 16));
                    bx += bf2f((u16)g2) + bf2f((u16)g3);
                    by += bf2f((u16)(g2 >> 16)) + bf2f((u16)(g3 >> 16));
                }
                for (; e < end; e += 2) {
                    u32 g = qprev[(size_t)srcs[e] * 32 + c];
                    ax += bf2f((u16)g);
                    ay += bf2f((u16)(g >> 16));
                }
            }
            ax += bx; ay += by;
            ax += __shfl_xor(ax, 32);
            ay += __shfl_xor(ay, 32);
            if (half == 0) {
                float hx = 0.f, hy = 0.f;
                if (node < NN) {
                    u32 wp = pw2p[(size_t)node * 32 + c];
                    hx = ax + bf2f((u16)wp) + bp.x;
                    hy = ay + bf2f((u16)(wp >> 16)) + bp.y;
                }
                H32[(wave * 16 + i) * 36 + c] = pack2bf(hx, hy);
            }
        }
    }
    __syncthreads();   // bar0: H visible

    // ---- stage 1: p = relu(h @ Wpt + b_pre) -> ts (A from Hs, stride 72 u16) ----
    {
        ffrag acc[4][4];
#pragma unroll
        for (int mt = 0; mt < 4; mt++)
#pragma unroll
            for (int nt = 0; nt < 4; nt++) acc[mt][nt] = (ffrag)0.f;
#pragma unroll
        for (int ch = 0; ch < 2; ch++) {
            const int kb = ch * 32 + quad * 8;
            bfrag a[4], b[4];
#pragma unroll
            for (int mt = 0; mt < 4; mt++)
                a[mt] = *(const bfrag*)(Hs + (mt * 16 + l16) * 72 + kb);
#pragma unroll
            for (int nt = 0; nt < 4; nt++)
                b[nt] = *(const bfrag*)(Wpt + (size_t)(wave * 64 + nt * 16 + l16) * FS + kb);
#pragma unroll
            for (int mt = 0; mt < 4; mt++)
#pragma unroll
                for (int nt = 0; nt < 4; nt++)
                    acc[mt][nt] = __builtin_amdgcn_mfma_f32_16x16x32_bf16(a[mt], b[nt], acc[mt][nt], 0, 0, 0);
        }
#pragma unroll
        for (int nt = 0; nt < 4; nt++) {
            const int col = wave * 64 + nt * 16 + l16;
            const float bv = b_pre[col];
#pragma unroll
            for (int mt = 0; mt < 4; mt++)
#pragma unroll
                for (int r = 0; r < 4; r++)
                    ts[(mt * 16 + quad * 4 + r) * 264 + col] = f2bf(fmaxf(acc[mt][nt][r] + bv, 0.f));
        }
    }
    __syncthreads();   // bar1: p visible

    // ---- stage 2: m = relu(p@Wct+bc), pw2 = p@Wp2 ----
    ffrag accm[4][4];
    ffrag accw[4];
    {
#pragma unroll
        for (int mt = 0; mt < 4; mt++) {
            accw[mt] = (ffrag)0.f;
#pragma unroll
            for (int nt = 0; nt < 4; nt++) accm[mt][nt] = (ffrag)0.f;
        }
        bfrag b[2][4], bw[2];
        {
            const int kb0 = quad * 8;
#pragma unroll
            for (int nt = 0; nt < 4; nt++)
                b[0][nt] = *(const bfrag*)(Wct + (size_t)(wave * 64 + nt * 16 + l16) * HH + kb0);
            bw[0] = *(const bfrag*)(Wp2t + (size_t)(wave * 16 + l16) * HH + kb0);
        }
#pragma unroll
        for (int ch = 0; ch < 8; ch++) {
            const int cur = ch & 1, nxt = cur ^ 1;
            if (ch < 7) {
                const int kb2 = (ch + 1) * 32 + quad * 8;
#pragma unroll
                for (int nt = 0; nt < 4; nt++)
                    b[nxt][nt] = *(const bfrag*)(Wct + (size_t)(wave * 64 + nt * 16 + l16) * HH + kb2);
                bw[nxt] = *(const bfrag*)(Wp2t + (size_t)(wave * 16 + l16) * HH + kb2);
            }
            const int kb = ch * 32 + quad * 8;
            bfrag a[4];
#pragma unroll
            for (int mt = 0; mt < 4; mt++)
                a[mt] = *(const bfrag*)(ts + (mt * 16 + l16) * 264 + kb);
#pragma unroll
            for (int mt = 0; mt < 4; mt++) {
#pragma unroll
                for (int nt = 0; nt < 4; nt++)
                    accm[mt][nt] = __builtin_amdgcn_mfma_f32_16x16x32_bf16(a[mt], b[cur][nt], accm[mt][nt], 0, 0, 0);
                accw[mt] = __builtin_amdgcn_mfma_f32_16x16x32_bf16(a[mt], bw[cur], accw[mt], 0, 0, 0);
            }
        }
    }
    __syncthreads();   // bar2: p reads done (WAR before m overwrites ts; H dead -> stA alias OK)

    // ---- write m -> ts, pw2 -> stA(=Hs) ----
    {
        u16* stA = Hs;
#pragma unroll
        for (int nt = 0; nt < 4; nt++) {
            const int col = wave * 64 + nt * 16 + l16;
            const float bv = b_conv[col];
#pragma unroll
            for (int mt = 0; mt < 4; mt++)
#pragma unroll
                for (int r = 0; r < 4; r++)
                    ts[(mt * 16 + quad * 4 + r) * 264 + col] = f2bf(fmaxf(accm[mt][nt][r] + bv, 0.f));
        }
        const int colw = wave * 16 + l16;
#pragma unroll
        for (int mt = 0; mt < 4; mt++)
#pragma unroll
            for (int r = 0; r < 4; r++)
                stA[(mt * 16 + quad * 4 + r) * 72 + colw] = f2bf(accw[mt][r]);
    }
    __syncthreads();   // bar3: m and stA visible

    // ---- coalesced pw2 store ----
#pragma unroll
    for (int s = 0; s < 2; s++) {
        const int j = t + s * 256;
        const int row = j >> 3, seg = j & 7;
        uint4 v = *(const uint4*)(Hs + row * 72 + seg * 8);
        *(uint4*)(pw2o + (size_t)(nodeBase + row) * FS + seg * 8) = v;
    }

    // ---- stage 3: q = m @ Wz ----
    {
        ffrag qa[4];
#pragma unroll
        for (int mt = 0; mt < 4; mt++) qa[mt] = (ffrag)0.f;
        bfrag bz[2];
        bz[0] = *(const bfrag*)(Wzt + (size_t)(wave * 16 + l16) * HH + quad * 8);
#pragma unroll
        for (int ch = 0; ch < 8; ch++) {
            const int cur = ch & 1;
            if (ch < 7)
                bz[cur ^ 1] = *(const bfrag*)(Wzt + (size_t)(wave * 16 + l16) * HH + (ch + 1) * 32 + quad * 8);
            const int kb = ch * 32 + quad * 8;
#pragma unroll
            for (int mt = 0; mt < 4; mt++) {
                bfrag am = *(const bfrag*)(ts + (mt * 16 + l16) * 264 + kb);
                qa[mt] = __builtin_amdgcn_mfma_f32_16x16x32_bf16(am, bz[cur], qa[mt], 0, 0, 0);
            }
        }
        const int col = wave * 16 + l16;
#pragma unroll
        for (int mt = 0; mt < 4; mt++)
#pragma unroll
            for (int r = 0; r < 4; r++)
                stB[(mt * 16 + quad * 4 + r) * 72 + col] = f2bf(qa[mt][r]);
    }
    __syncthreads();   // bar4: stB visible

    // ---- coalesced q store ----
#pragma unroll
    for (int s = 0; s < 2; s++) {
        const int j = t + s * 256;
        const int row = j >> 3, seg = j & 7;
        uint4 v = *(const uint4*)(stB + row * 72 + seg * 8);
        *(uint4*)(qbf + (size_t)(nodeBase + row) * FS + seg * 8) = v;
    }
}

// ---------------- final aggregation (fp32 out; r12 exact) ----------------
__global__ __launch_bounds__(256) void agg_k(const u32* __restrict__ q2,
                                             const int* __restrict__ offsets,
                                             const int* __restrict__ srcs,
                                             const u32* __restrict__ pw2,
                                             const float* __restrict__ b_post,
                                             float* __restrict__ outf) {
    const int wave = threadIdx.x >> 6;
    const int lane = threadIdx.x & 63;
    const int node = blockIdx.x * 4 + wave;
    const int half = lane >> 5, c = lane & 31;
    const int beg = offsets[node], end = offsets[node + 1];
    float ax = 0.f, ay = 0.f, bx = 0.f, by = 0.f;
    int e = beg + half;
    for (; e + 6 < end; e += 8) {
        int s0 = srcs[e], s1 = srcs[e + 2], s2 = srcs[e + 4], s3 = srcs[e + 6];
        u32 g0 = q2[(size_t)s0 * 32 + c];
        u32 g1 = q2[(size_t)s1 * 32 + c];
        u32 g2 = q2[(size_t)s2 * 32 + c];
        u32 g3 = q2[(size_t)s3 * 32 + c];
        ax += bf2f((u16)g0) + bf2f((u16)g1);
        ay += bf2f((u16)(g0 >> 16)) + bf2f((u16)(g1 >> 16));
        bx += bf2f((u16)g2) + bf2f((u16)g3);
        by += bf2f((u16)(g2 >> 16)) + bf2f((u16)(g3 >> 16));
    }
    for (; e < end; e += 2) {
        u32 g = q2[(size_t)srcs[e] * 32 + c];
        ax += bf2f((u16)g);
        ay += bf2f((u16)(g >> 16));
    }
    ax += bx; ay += by;
    ax += __shfl_xor(ax, 32);
    ay += __shfl_xor(ay, 32);
    if (half == 0) {
        u32 wp = pw2[(size_t)node * 32 + c];
        float2 b = *(const float2*)&b_post[2 * c];
        float hx = ax + bf2f((u16)wp) + b.x;
        float hy = ay + bf2f((u16)(wp >> 16)) + b.y;
        *(float2*)&outf[(size_t)node * FS + 2 * c] = make_float2(hx, hy);
    }
}

extern "C" void kernel_launch(void* const* d_in, const int* in_sizes, int n_in,
                              void* d_out, int out_size, void* d_ws, size_t ws_size,
                              hipStream_t stream) {
    const float* x      = (const float*)d_in[0];
    const int*   ei     = (const int*)d_in[1];
    const float* W_pre  = (const float*)d_in[2];
    const float* b_pre  = (const float*)d_in[3];
    const float* W_conv = (const float*)d_in[4];
    const float* b_conv = (const float*)d_in[5];
    const float* W_post = (const float*)d_in[6];
    const float* b_post = (const float*)d_in[7];
    float* out = (float*)d_out;

    char* ws = (char*)d_ws;
    size_t off = 0;
    auto alloc = [&](size_t bytes) -> char* {
        char* r = ws + off;
        off += (bytes + 255) & ~(size_t)255;
        return r;
    };
    u16* hbf     = (u16*)alloc((size_t)NPAD * FS * 2);    // 12.8 MB
    u16* qA      = (u16*)alloc((size_t)NPAD * FS * 2);    // 12.8 MB
    u16* qB      = (u16*)alloc((size_t)NPAD * FS * 2);    // 12.8 MB
    u16* pw2     = (u16*)alloc((size_t)NPAD * FS * 2);    // 12.8 MB
    u32* tmp     = (u32*)alloc((size_t)NE * 4);           //  6.4 MB
    int* offsets = (int*)alloc((size_t)(NN + 1) * 4);
    int* srcs    = (int*)alloc((size_t)NE * 4);           //  6.4 MB
    int* cntM    = (int*)alloc((size_t)NBK2 * GA * 4);
    int* offM    = (int*)alloc((size_t)NBK2 * GA * 4);
    int* bstart  = (int*)alloc((size_t)(NBK2 + 1) * 4);
    u16* Wpt     = (u16*)alloc((size_t)HH * FS * 2);
    u16* Wct     = (u16*)alloc((size_t)HH * HH * 2);
    u16* Wzt     = (u16*)alloc((size_t)FS * HH * 2);
    u16* Wp2t    = (u16*)alloc((size_t)FS * HH * 2);
    (void)ws_size; (void)in_sizes; (void)n_in; (void)out_size;

    const int* dst = ei;       // edge_index[0] = aggregation targets
    const int* src = ei + NE;  // edge_index[1] = message sources

    cvt_x_k<<<(NN * FS / 4 + 255) / 256, 256, 0, stream>>>((const float4*)x, (uint2*)hbf, NN * FS / 4);
    prep_w_k<<<448, 256, 0, stream>>>(W_pre, W_conv, W_post, Wpt, Wct, Wzt, Wp2t);

    fillA_k<<<GA, 256, 0, stream>>>(dst, src, cntM, offM, tmp);
    bscan_k<<<1, 256, 0, stream>>>(cntM, bstart);
    fillB_k<<<NBK2, 256, 0, stream>>>(tmp, cntM, offM, bstart, offsets, srcs);
    final_off_k<<<1, 64, 0, stream>>>(offsets);

    const int GB128 = (NN + 127) / 128;  // 782
    const int GB64  = (NN + 63) / 64;    // 1563

    // step 0: transform from x
    xform_k<<<GB128, 512, 0, stream>>>(hbf, Wpt, b_pre, Wct, b_conv, Wzt, Wp2t, qA, pw2);
    // steps 1..3: fused gather + transform (q ping-pong; pw2 in-place per-row)
    fxform_k<<<GB64, 256, 0, stream>>>((const u32*)qA, offsets, srcs, (const u32*)pw2, b_post,
                                       Wpt, b_pre, Wct, b_conv, Wzt, Wp2t, qB, pw2);
    fxform_k<<<GB64, 256, 0, stream>>>((const u32*)qB, offsets, srcs, (const u32*)pw2, b_post,
                                       Wpt, b_pre, Wct, b_conv, Wzt, Wp2t, qA, pw2);
    fxform_k<<<GB64, 256, 0, stream>>>((const u32*)qA, offsets, srcs, (const u32*)pw2, b_post,
                                       Wpt, b_pre, Wct, b_conv, Wzt, Wp2t, qB, pw2);
    // final: h(4) in fp32
    agg_k<<<NN / 4, 256, 0, stream>>>((const u32*)qB, offsets, srcs, (const u32*)pw2, b_post, out);
}

// Round 11
// 580.607 us; speedup vs baseline: 1.4412x; 1.4412x over previous
//
#include <hip/hip_runtime.h>

// GNNCASimple — fused per-node pipeline (bf16 MFMA, fp32 accum), fp32 I/O.
// r22: REVERT to r19 (verified 605.3us) after r21's shfl-srcs agg FAILED
// correctness (absmax 312 > 70.4; baseline 24). Edge-coverage of r21 was
// provably identical to r12 -> defect isolated to per-lane-divergent __shfl
// (ds_bpermute) inside half-divergent trip-count loops; exact mechanism
// unresolved => do not ship (rigor). agg body restored to the twice-verified
// r12 form + one safe tweak: pw2/b_post epilogue loads hoisted above the
// gather loop (broadcast-coalesced, latency hides under gather).
// Model update: agg gather = random 128B L3 reads at ~3.3TB/s with >10x more
// concurrency available than needed -> fabric-floor-bound, NOT latency-bound
// (r14 16-deep null + r21 analysis). fp8-q traffic cut fails error budget.
// agg is at its floor; xform at the 2-barrier structural floor for this size.
// xform = r19 exact (128-node tile, 8 waves, 63us); CSR unchanged.

#define NN 100000
#define NPAD 100096               // 782 * 128
#define FS 64
#define HH 256
#define NE 1600000
#define NSTEPS 4
#define GA 128                    // fillA blocks
#define EPB (NE / GA)             // 12500 edges per fillA block
#define BK2SH 9                   // log2(nodes per coarse bucket)
#define BS2 (1 << BK2SH)          // 512
#define NBK2 ((NN + BS2 - 1) / BS2)   // 196 buckets

typedef unsigned short u16;
typedef unsigned int u32;
typedef __attribute__((ext_vector_type(8))) short bfrag;   // 8 bf16 = 4 VGPRs (MFMA A/B)
typedef __attribute__((ext_vector_type(4))) float ffrag;   // 4 fp32 (MFMA C/D)

static __device__ __forceinline__ u16 f2bf(float f) {  // RNE
    union { float f; u32 u; } v; v.f = f;
    return (u16)((v.u + 0x7fffu + ((v.u >> 16) & 1u)) >> 16);
}
static __device__ __forceinline__ float bf2f(u16 h) {
    union { u32 u; float f; } v; v.u = (u32)h << 16; return v.f;
}
static __device__ __forceinline__ u32 pack2bf(float a, float b) {
    return (u32)f2bf(a) | ((u32)f2bf(b) << 16);
}

// ---------------- x (fp32) -> hbf (bf16) ----------------
__global__ void cvt_x_k(const float4* __restrict__ x, uint2* __restrict__ hbf, int n4) {
    int i = blockIdx.x * 256 + threadIdx.x;
    if (i < n4) {
        float4 v = x[i];
        hbf[i] = make_uint2(pack2bf(v.x, v.y), pack2bf(v.z, v.w));
    }
}

// ---------------- all weight transposes (fp32 [K][C] -> bf16 [C][K]) ----------------
__global__ void prep_w_k(const float* __restrict__ W_pre, const float* __restrict__ W_conv,
                         const float* __restrict__ W_post,
                         u16* __restrict__ Wpt, u16* __restrict__ Wct,
                         u16* __restrict__ Wzt, u16* __restrict__ Wp2t) {
    int i = blockIdx.x * 256 + threadIdx.x;
    if (i < 65536) {                       // Wct [256][256]
        int c = i >> 8, k = i & 255;
        Wct[i] = f2bf(W_conv[k * HH + c]);
    } else if (i < 81920) {                // Wpt [256][64]
        int j = i - 65536;
        int c = j >> 6, k = j & 63;
        Wpt[j] = f2bf(W_pre[k * HH + c]);
    } else if (i < 98304) {                // Wzt [64][256]
        int j = i - 81920;
        int c = j >> 8, k = j & 255;
        Wzt[j] = f2bf(W_post[k * FS + c]);
    } else if (i < 114688) {               // Wp2t [64][256]
        int j = i - 98304;
        int c = j >> 8, k = j & 255;
        Wp2t[j] = f2bf(W_post[(HH + k) * FS + c]);
    }
}

// ---------------- fillA ----------------
__global__ __launch_bounds__(256) void fillA_k(const int* __restrict__ dst, const int* __restrict__ src,
                                               int* __restrict__ cntM, int* __restrict__ offM,
                                               u32* __restrict__ tmp) {
    __shared__ int cnt[256];
    __shared__ int sc[256];
    __shared__ int cur[256];
    const int t = threadIdx.x, b = blockIdx.x;
    const int e0 = b * EPB;
    cnt[t] = 0;
    __syncthreads();
    for (int i = t; i < EPB; i += 256) atomicAdd(&cnt[dst[e0 + i] >> BK2SH], 1);
    __syncthreads();
    int v = cnt[t];
    sc[t] = v;
    __syncthreads();
    for (int o = 1; o < 256; o <<= 1) {
        int y = (t >= o) ? sc[t - o] : 0;
        __syncthreads();
        sc[t] += y;
        __syncthreads();
    }
    int excl = sc[t] - v;
    cur[t] = excl;
    if (t < NBK2) {
        cntM[t * GA + b] = v;
        offM[t * GA + b] = excl;
    }
    __syncthreads();
    u32* seg = tmp + (size_t)b * EPB;
    for (int i = t; i < EPB; i += 256) {
        int d = dst[e0 + i], s = src[e0 + i];
        int pos = atomicAdd(&cur[d >> BK2SH], 1);
        seg[pos] = ((u32)(d & (BS2 - 1)) << 23) | (u32)s;
    }
}

// ---------------- bscan ----------------
__global__ void bscan_k(const int* __restrict__ cntM, int* __restrict__ bstart) {
    __shared__ int sh[256];
    const int t = threadIdx.x;
    int tot = 0;
    if (t < NBK2)
        for (int b = 0; b < GA; b++) tot += cntM[t * GA + b];
    sh[t] = tot;
    __syncthreads();
    for (int o = 1; o < 256; o <<= 1) {
        int y = (t >= o) ? sh[t - o] : 0;
        __syncthreads();
        sh[t] += y;
        __syncthreads();
    }
    if (t < NBK2) bstart[t] = sh[t] - tot;
    if (t == 255) bstart[NBK2] = sh[255];
}

// ---------------- fillB ----------------
__global__ __launch_bounds__(256) void fillB_k(const u32* __restrict__ tmp,
                                               const int* __restrict__ cntM, const int* __restrict__ offM,
                                               const int* __restrict__ bstart,
                                               int* __restrict__ offsets, int* __restrict__ srcs) {
    __shared__ int cnt[BS2];
    __shared__ int cur[BS2];
    __shared__ int runlen[GA];
    __shared__ int runoff[GA];
    const int t = threadIdx.x, k = blockIdx.x;
    const int nodeBase = k << BK2SH;
    cnt[t] = 0;
    cnt[t + 256] = 0;
    if (t < GA) {
        runlen[t] = cntM[k * GA + t];
        runoff[t] = offM[k * GA + t];
    }
    __syncthreads();
    const int rsub = t >> 6;
    const int elane = t & 63;
    for (int g = 0; g < GA / 4; g++) {
        int rb = g * 4 + rsub;
        int len = runlen[rb];
        const u32* run = tmp + (size_t)rb * EPB + runoff[rb];
        for (int e = elane; e < len; e += 64) atomicAdd(&cnt[run[e] >> 23], 1);
    }
    __syncthreads();
    int a = cnt[2 * t], b2 = cnt[2 * t + 1];
    int s = a + b2;
    cur[t] = s;
    __syncthreads();
    for (int o = 1; o < 256; o <<= 1) {
        int y = (t >= o) ? cur[t - o] : 0;
        __syncthreads();
        cur[t] += y;
        __syncthreads();
    }
    int exclPair = cur[t] - s;
    __syncthreads();
    const int base = bstart[k];
    int o0 = base + exclPair;
    int o1 = o0 + a;
    int n0 = nodeBase + 2 * t, n1 = n0 + 1;
    if (n0 < NN) offsets[n0] = o0;
    if (n1 < NN) offsets[n1] = o1;
    cur[2 * t] = o0;
    cur[2 * t + 1] = o1;
    __syncthreads();
    for (int g = 0; g < GA / 4; g++) {
        int rb = g * 4 + rsub;
        int len = runlen[rb];
        const u32* run = tmp + (size_t)rb * EPB + runoff[rb];
        for (int e = elane; e < len; e += 64) {
            u32 p = run[e];
            int pos = atomicAdd(&cur[p >> 23], 1);
            srcs[pos] = (int)(p & 0x7FFFFFu);
        }
    }
}

__global__ void final_off_k(int* __restrict__ offsets) {
    if (threadIdx.x == 0) offsets[NN] = NE;
}

// ---------------- fused node transform (r19 exact: 128-node tile, 8 waves) ----------------
__global__ __launch_bounds__(512, 4) void xform_k(const u16* __restrict__ hbf,     // [NPAD][64]
                                                  const u16* __restrict__ Wpt,
                                                  const float* __restrict__ b_pre,
                                                  const u16* __restrict__ Wct,
                                                  const float* __restrict__ b_conv,
                                                  const u16* __restrict__ Wzt,
                                                  const u16* __restrict__ Wp2t,
                                                  u16* __restrict__ qbf,
                                                  u16* __restrict__ pw2o) {
    __shared__ __align__(16) u16 ts[128 * 264];
    const int t = threadIdx.x;
    const int w = t >> 6, lane = t & 63;
    const int quad = lane >> 4, l16 = lane & 15;
    const int whi = w >> 2;
    const int cw = (w & 3) * 16;
    const int rh = whi * 64;
    const int nodeBase = blockIdx.x * 128;

    {
        ffrag acc[8][2];
#pragma unroll
        for (int mt = 0; mt < 8; mt++) { acc[mt][0] = (ffrag)0.f; acc[mt][1] = (ffrag)0.f; }
#pragma unroll
        for (int ch = 0; ch < 2; ch++) {
            const int kb = ch * 32 + quad * 8;
            bfrag b0 = *(const bfrag*)(Wpt + (size_t)(w * 32 + l16) * FS + kb);
            bfrag b1 = *(const bfrag*)(Wpt + (size_t)(w * 32 + 16 + l16) * FS + kb);
#pragma unroll
            for (int mt = 0; mt < 8; mt++) {
                bfrag a = *(const bfrag*)(hbf + (size_t)(nodeBase + mt * 16 + l16) * FS + kb);
                acc[mt][0] = __builtin_amdgcn_mfma_f32_16x16x32_bf16(a, b0, acc[mt][0], 0, 0, 0);
                acc[mt][1] = __builtin_amdgcn_mfma_f32_16x16x32_bf16(a, b1, acc[mt][1], 0, 0, 0);
            }
        }
#pragma unroll
        for (int nt = 0; nt < 2; nt++) {
            const int col = w * 32 + nt * 16 + l16;
            const float bv = b_pre[col];
#pragma unroll
            for (int mt = 0; mt < 8; mt++)
#pragma unroll
                for (int r = 0; r < 4; r++)
                    ts[(mt * 16 + quad * 4 + r) * 264 + col] = f2bf(fmaxf(acc[mt][nt][r] + bv, 0.f));
        }
    }
    __syncthreads();

    ffrag accm[8][2];
    ffrag accw[4];
    {
#pragma unroll
        for (int mt = 0; mt < 8; mt++) { accm[mt][0] = (ffrag)0.f; accm[mt][1] = (ffrag)0.f; }
#pragma unroll
        for (int mt = 0; mt < 4; mt++) accw[mt] = (ffrag)0.f;
#pragma unroll
        for (int ch = 0; ch < 8; ch++) {
            const int kb = ch * 32 + quad * 8;
            bfrag b0 = *(const bfrag*)(Wct + (size_t)(w * 32 + l16) * HH + kb);
            bfrag b1 = *(const bfrag*)(Wct + (size_t)(w * 32 + 16 + l16) * HH + kb);
            bfrag bw = *(const bfrag*)(Wp2t + (size_t)(cw + l16) * HH + kb);
            {
                bfrag a0 = *(const bfrag*)(ts + (0 * 16 + l16) * 264 + kb);
                bfrag a1 = *(const bfrag*)(ts + (1 * 16 + l16) * 264 + kb);
                bfrag a2 = *(const bfrag*)(ts + (2 * 16 + l16) * 264 + kb);
                bfrag a3 = *(const bfrag*)(ts + (3 * 16 + l16) * 264 + kb);
                if (whi == 0) {
                    accw[0] = __builtin_amdgcn_mfma_f32_16x16x32_bf16(a0, bw, accw[0], 0, 0, 0);
                    accw[1] = __builtin_amdgcn_mfma_f32_16x16x32_bf16(a1, bw, accw[1], 0, 0, 0);
                    accw[2] = __builtin_amdgcn_mfma_f32_16x16x32_bf16(a2, bw, accw[2], 0, 0, 0);
                    accw[3] = __builtin_amdgcn_mfma_f32_16x16x32_bf16(a3, bw, accw[3], 0, 0, 0);
                }
                accm[0][0] = __builtin_amdgcn_mfma_f32_16x16x32_bf16(a0, b0, accm[0][0], 0, 0, 0);
                accm[0][1] = __builtin_amdgcn_mfma_f32_16x16x32_bf16(a0, b1, accm[0][1], 0, 0, 0);
                accm[1][0] = __builtin_amdgcn_mfma_f32_16x16x32_bf16(a1, b0, accm[1][0], 0, 0, 0);
                accm[1][1] = __builtin_amdgcn_mfma_f32_16x16x32_bf16(a1, b1, accm[1][1], 0, 0, 0);
                accm[2][0] = __builtin_amdgcn_mfma_f32_16x16x32_bf16(a2, b0, accm[2][0], 0, 0, 0);
                accm[2][1] = __builtin_amdgcn_mfma_f32_16x16x32_bf16(a2, b1, accm[2][1], 0, 0, 0);
                accm[3][0] = __builtin_amdgcn_mfma_f32_16x16x32_bf16(a3, b0, accm[3][0], 0, 0, 0);
                accm[3][1] = __builtin_amdgcn_mfma_f32_16x16x32_bf16(a3, b1, accm[3][1], 0, 0, 0);
            }
            {
                bfrag a4 = *(const bfrag*)(ts + (4 * 16 + l16) * 264 + kb);
                bfrag a5 = *(const bfrag*)(ts + (5 * 16 + l16) * 264 + kb);
                bfrag a6 = *(const bfrag*)(ts + (6 * 16 + l16) * 264 + kb);
                bfrag a7 = *(const bfrag*)(ts + (7 * 16 + l16) * 264 + kb);
                if (whi == 1) {
                    accw[0] = __builtin_amdgcn_mfma_f32_16x16x32_bf16(a4, bw, accw[0], 0, 0, 0);
                    accw[1] = __builtin_amdgcn_mfma_f32_16x16x32_bf16(a5, bw, accw[1], 0, 0, 0);
                    accw[2] = __builtin_amdgcn_mfma_f32_16x16x32_bf16(a6, bw, accw[2], 0, 0, 0);
                    accw[3] = __builtin_amdgcn_mfma_f32_16x16x32_bf16(a7, bw, accw[3], 0, 0, 0);
                }
                accm[4][0] = __builtin_amdgcn_mfma_f32_16x16x32_bf16(a4, b0, accm[4][0], 0, 0, 0);
                accm[4][1] = __builtin_amdgcn_mfma_f32_16x16x32_bf16(a4, b1, accm[4][1], 0, 0, 0);
                accm[5][0] = __builtin_amdgcn_mfma_f32_16x16x32_bf16(a5, b0, accm[5][0], 0, 0, 0);
                accm[5][1] = __builtin_amdgcn_mfma_f32_16x16x32_bf16(a5, b1, accm[5][1], 0, 0, 0);
                accm[6][0] = __builtin_amdgcn_mfma_f32_16x16x32_bf16(a6, b0, accm[6][0], 0, 0, 0);
                accm[6][1] = __builtin_amdgcn_mfma_f32_16x16x32_bf16(a6, b1, accm[6][1], 0, 0, 0);
                accm[7][0] = __builtin_amdgcn_mfma_f32_16x16x32_bf16(a7, b0, accm[7][0], 0, 0, 0);
                accm[7][1] = __builtin_amdgcn_mfma_f32_16x16x32_bf16(a7, b1, accm[7][1], 0, 0, 0);
            }
        }
    }
    __syncthreads();

    {
#pragma unroll
        for (int nt = 0; nt < 2; nt++) {
            const int col = w * 32 + nt * 16 + l16;
            const float bv = b_conv[col];
#pragma unroll
            for (int mt = 0; mt < 8; mt++)
#pragma unroll
                for (int r = 0; r < 4; r++)
                    ts[(mt * 16 + quad * 4 + r) * 264 + col] = f2bf(fmaxf(accm[mt][nt][r] + bv, 0.f));
        }
    }
    __syncthreads();

    ffrag qa[4];
    {
#pragma unroll
        for (int mt = 0; mt < 4; mt++) qa[mt] = (ffrag)0.f;
#pragma unroll
        for (int ch = 0; ch < 8; ch++) {
            const int kb = ch * 32 + quad * 8;
            bfrag bz = *(const bfrag*)(Wzt + (size_t)(cw + l16) * HH + kb);
#pragma unroll
            for (int mt = 0; mt < 4; mt++) {
                bfrag am = *(const bfrag*)(ts + (rh + mt * 16 + l16) * 264 + kb);
                qa[mt] = __builtin_amdgcn_mfma_f32_16x16x32_bf16(am, bz, qa[mt], 0, 0, 0);
            }
        }
    }
    __syncthreads();

    {
        u16* stgP = ts;
        u16* stgQ = ts + 128 * 72;
#pragma unroll
        for (int mt = 0; mt < 4; mt++)
#pragma unroll
            for (int r = 0; r < 4; r++) {
                const int row = rh + mt * 16 + quad * 4 + r;
                stgP[row * 72 + cw + l16] = f2bf(accw[mt][r]);
                stgQ[row * 72 + cw + l16] = f2bf(qa[mt][r]);
            }
    }
    __syncthreads();

    {
        const u16* stgP = ts;
        const u16* stgQ = ts + 128 * 72;
#pragma unroll
        for (int s = 0; s < 2; s++) {
            const int j = t + s * 512;
            const int row = j >> 3, seg = j & 7;
            if (nodeBase + row < NN) {
                uint4 vp = *(const uint4*)(stgP + row * 72 + seg * 8);
                uint4 vq = *(const uint4*)(stgQ + row * 72 + seg * 8);
                *(uint4*)(pw2o + (size_t)(nodeBase + row) * FS + seg * 8) = vp;
                *(uint4*)(qbf + (size_t)(nodeBase + row) * FS + seg * 8) = vq;
            }
        }
    }
}

// ---------------- aggregation + h-build (r12 body; r22: pw2/b_post prefetch hoist) ----------------
__global__ __launch_bounds__(256) void agg_k(const u32* __restrict__ q2,  // [NPAD][32] packed bf16 pairs
                                             const int* __restrict__ offsets,
                                             const int* __restrict__ srcs,
                                             const u32* __restrict__ pw2, // [NPAD][32] packed bf16 pairs
                                             const float* __restrict__ b_post,
                                             u32* __restrict__ hbf_out,   // [NPAD][32] packed (steps 0..2)
                                             float* __restrict__ outf) {  // [NN][64] (last step)
    const int wave = threadIdx.x >> 6;
    const int lane = threadIdx.x & 63;
    const int node = blockIdx.x * 4 + wave;
    const int half = lane >> 5, c = lane & 31;
    const int beg = offsets[node], end = offsets[node + 1];
    // prefetch epilogue operands: latency hides under the gather loop
    const u32 wp = pw2[(size_t)node * 32 + c];
    const float2 bp = *(const float2*)&b_post[2 * c];
    float ax = 0.f, ay = 0.f, bx = 0.f, by = 0.f;
    int e = beg + half;
    for (; e + 6 < end; e += 8) {
        int s0 = srcs[e], s1 = srcs[e + 2], s2 = srcs[e + 4], s3 = srcs[e + 6];
        u32 g0 = q2[(size_t)s0 * 32 + c];
        u32 g1 = q2[(size_t)s1 * 32 + c];
        u32 g2 = q2[(size_t)s2 * 32 + c];
        u32 g3 = q2[(size_t)s3 * 32 + c];
        ax += bf2f((u16)g0) + bf2f((u16)g1);
        ay += bf2f((u16)(g0 >> 16)) + bf2f((u16)(g1 >> 16));
        bx += bf2f((u16)g2) + bf2f((u16)g3);
        by += bf2f((u16)(g2 >> 16)) + bf2f((u16)(g3 >> 16));
    }
    for (; e < end; e += 2) {
        u32 g = q2[(size_t)srcs[e] * 32 + c];
        ax += bf2f((u16)g);
        ay += bf2f((u16)(g >> 16));
    }
    ax += bx; ay += by;
    ax += __shfl_xor(ax, 32);
    ay += __shfl_xor(ay, 32);
    if (half == 0) {
        float hx = ax + bf2f((u16)wp) + bp.x;
        float hy = ay + bf2f((u16)(wp >> 16)) + bp.y;
        if (outf) {
            *(float2*)&outf[(size_t)node * FS + 2 * c] = make_float2(hx, hy);
        } else {
            hbf_out[(size_t)node * 32 + c] = pack2bf(hx, hy);
        }
    }
}

extern "C" void kernel_launch(void* const* d_in, const int* in_sizes, int n_in,
                              void* d_out, int out_size, void* d_ws, size_t ws_size,
                              hipStream_t stream) {
    const float* x      = (const float*)d_in[0];
    const int*   ei     = (const int*)d_in[1];
    const float* W_pre  = (const float*)d_in[2];
    const float* b_pre  = (const float*)d_in[3];
    const float* W_conv = (const float*)d_in[4];
    const float* b_conv = (const float*)d_in[5];
    const float* W_post = (const float*)d_in[6];
    const float* b_post = (const float*)d_in[7];
    float* out = (float*)d_out;

    char* ws = (char*)d_ws;
    size_t off = 0;
    auto alloc = [&](size_t bytes) -> char* {
        char* r = ws + off;
        off += (bytes + 255) & ~(size_t)255;
        return r;
    };
    u16* hbf     = (u16*)alloc((size_t)NPAD * FS * 2);    // 12.8 MB
    u16* qbf     = (u16*)alloc((size_t)NPAD * FS * 2);    // 12.8 MB
    u16* pw2     = (u16*)alloc((size_t)NPAD * FS * 2);    // 12.8 MB
    u32* tmp     = (u32*)alloc((size_t)NE * 4);           //  6.4 MB
    int* offsets = (int*)alloc((size_t)(NN + 1) * 4);
    int* srcs    = (int*)alloc((size_t)NE * 4);           //  6.4 MB
    int* cntM    = (int*)alloc((size_t)NBK2 * GA * 4);
    int* offM    = (int*)alloc((size_t)NBK2 * GA * 4);
    int* bstart  = (int*)alloc((size_t)(NBK2 + 1) * 4);
    u16* Wpt     = (u16*)alloc((size_t)HH * FS * 2);      // [256][64]
    u16* Wct     = (u16*)alloc((size_t)HH * HH * 2);      // [256][256]
    u16* Wzt     = (u16*)alloc((size_t)FS * HH * 2);      // [64][256]
    u16* Wp2t    = (u16*)alloc((size_t)FS * HH * 2);      // [64][256]
    (void)ws_size; (void)in_sizes; (void)n_in; (void)out_size;

    const int* dst = ei;       // edge_index[0] = aggregation targets
    const int* src = ei + NE;  // edge_index[1] = message sources

    cvt_x_k<<<(NN * FS / 4 + 255) / 256, 256, 0, stream>>>((const float4*)x, (uint2*)hbf, NN * FS / 4);
    prep_w_k<<<448, 256, 0, stream>>>(W_pre, W_conv, W_post, Wpt, Wct, Wzt, Wp2t);

    fillA_k<<<GA, 256, 0, stream>>>(dst, src, cntM, offM, tmp);
    bscan_k<<<1, 256, 0, stream>>>(cntM, bstart);
    fillB_k<<<NBK2, 256, 0, stream>>>(tmp, cntM, offM, bstart, offsets, srcs);
    final_off_k<<<1, 64, 0, stream>>>(offsets);

    const int GB = (NN + 127) / 128;  // 782
    for (int s = 0; s < NSTEPS; s++) {
        xform_k<<<GB, 512, 0, stream>>>(hbf, Wpt, b_pre, Wct, b_conv, Wzt, Wp2t, qbf, pw2);
        if (s < NSTEPS - 1)
            agg_k<<<NN / 4, 256, 0, stream>>>((const u32*)qbf, offsets, srcs, (const u32*)pw2, b_post,
                                              (u32*)hbf, nullptr);
        else
            agg_k<<<NN / 4, 256, 0, stream>>>((const u32*)qbf, offsets, srcs, (const u32*)pw2, b_post,
                                              nullptr, out);
    }
}